// Round 8
// baseline (220.813 us; speedup 1.0000x reference)
//
#include <hip/hip_runtime.h>

// LocallyConnected3DFlipout:
//   out[b,p,f] = sum_k patch[b,p,k]*loc[p,k,f]
//              + sign_out[b,p,f]*sum_k (x*sign_in)patch[b,p,k]*(softplus(rho)*eps)[p,k,f]
//              + bias[f]
// patch k = c*27 + (kd*9+kh*3+kw)  (channel slowest, spatial row-major fastest).
//
// R8: one wave per block, zero barriers.
// R7 (85 us) was still latency-bound (VALUBusy 30%, Occ 18%): all 4 waves of
// a 256-thread block were barrier-locked into the same stage/compute phase,
// and VGPR=124 -> only 4 blocks/CU of phase diversity. Fix: 64-thread blocks
// (1 wave) owning PPB=4 positions. A wave stages its own 7 KB LDS slab then
// computes -- same-wave LDS RAW is lgkmcnt-tracked, NO __syncthreads. 16
// independent waves/CU each at their own phase: staging overlaps compute
// across waves (m114 MFMA/VALU-style co-scheduling, here VMEM/VALU).
// Per-thread work is byte-identical to the verified R3 body.
// XCD-contiguous tiles kept from R7 (FETCH dropped 165->95 MB): 5488 = 8*686.
// Bank check: pl-stride 436 dw -> pl*20 mod 32 = {0,20,8,28}, disjoint;
// 16 lanes/pl broadcast -> conflict-free.
// bf16 weights verified: absmax 0.0156 vs 0.0578 threshold.

constexpr int Bn   = 32;
constexpr int Dn   = 30;
constexpr int Cn   = 4;
constexpr int ODn  = 28;
constexpr int Pn   = ODn * ODn * ODn;   // 21952
constexpr int Tt   = 27;
constexpr int Kn   = Tt * Cn;           // 108
constexpr int PPB  = 4;                 // positions per (wave-)block
constexpr int NT   = Pn / PPB;          // 5488 tiles = 8 XCDs x 686
constexpr int THREADS = 64;
constexpr int WSTRIDE = Kn + 1;         // 109 uint4 per p

__device__ __forceinline__ unsigned bf16rne(float f) {
    unsigned u = __float_as_uint(f);
    return (u + 0x7fffu + ((u >> 16) & 1u)) >> 16;
}
__device__ __forceinline__ float bflo(unsigned u) { return __uint_as_float(u << 16); }
__device__ __forceinline__ float bfhi(unsigned u) { return __uint_as_float(u & 0xffff0000u); }

__global__ __launch_bounds__(THREADS) void lc3d_flipout_kernel(
    const float* __restrict__ x,        // [B,30,30,30,4]
    const float* __restrict__ loc,      // [P,108,4]
    const float* __restrict__ rho,      // [P,108,4]
    const float* __restrict__ bias,     // [4]
    const float* __restrict__ eps,      // [P,108,4]
    const float* __restrict__ sgn_in,   // [B,30,30,30,4]
    const float* __restrict__ sgn_out,  // [B,P,4]
    float* __restrict__ out)            // [B,P,4]
{
    __shared__ uint4 wsh[PPB * WSTRIDE];   // 6976 B

    const int lane = threadIdx.x;

    // ---- XCD-contiguous tile map: block i -> xcd i&7 owns tiles
    //      [xcd*686, (xcd+1)*686). Concurrent x slab per XCD ~2.5 MB < 4 MB L2.
    const int tile   = (blockIdx.x & 7) * (NT / 8) + (blockIdx.x >> 3);
    const int p_base = tile * PPB;

    // ---- Stage weights: 432 uint4 (4 p x 108 k); coalesced 1 KB global runs;
    //      no barrier needed (single wave, lgkmcnt tracks LDS RAW). ----
    const float4* loc4 = (const float4*)loc + (size_t)p_base * Kn;
    const float4* rho4 = (const float4*)rho + (size_t)p_base * Kn;
    const float4* eps4 = (const float4*)eps + (size_t)p_base * Kn;
    for (int g = lane; g < PPB * Kn; g += THREADS) {
        const int plc = g / Kn;
        const int k   = g - plc * Kn;
        const float4 L = loc4[g];
        const float4 R = rho4[g];
        const float4 E = eps4[g];
        float nx = (R.x > 15.f ? R.x : __logf(1.f + __expf(R.x))) * E.x;
        float ny = (R.y > 15.f ? R.y : __logf(1.f + __expf(R.y))) * E.y;
        float nz = (R.z > 15.f ? R.z : __logf(1.f + __expf(R.z))) * E.z;
        float nw = (R.w > 15.f ? R.w : __logf(1.f + __expf(R.w))) * E.w;
        uint4 pk;
        pk.x = bf16rne(L.x) | (bf16rne(L.y) << 16);
        pk.y = bf16rne(L.z) | (bf16rne(L.w) << 16);
        pk.z = bf16rne(nx)  | (bf16rne(ny) << 16);
        pk.w = bf16rne(nz)  | (bf16rne(nw) << 16);
        wsh[plc * WSTRIDE + k] = pk;
    }

    // ---- Compute (verified R3 body): lane = (bh, pl), 2 batches/thread ----
    const int pl = lane & 3;
    const int bh = lane >> 2;           // 0..15
    const int b0 = bh, b1 = bh + 16;
    const int p  = p_base + pl;
    const int od = p / (ODn * ODn);
    const int prem = p - od * (ODn * ODn);
    const int oh = prem / ODn;
    const int ow = prem - oh * ODn;     // p_base%4==0, 28%4==0 -> ow..ow+3 same row
    const float4* x4 = (const float4*)x;
    const float4* s4 = (const float4*)sgn_in;
    const size_t v0 = (((size_t)b0 * Dn + od) * Dn + oh) * Dn + ow;
    const size_t v1 = (((size_t)b1 * Dn + od) * Dn + oh) * Dn + ow;
    const uint4* wp = wsh + pl * WSTRIDE;

    float a00=0.f,a01=0.f,a02=0.f,a03=0.f, a10=0.f,a11=0.f,a12=0.f,a13=0.f;
    float n00=0.f,n01=0.f,n02=0.f,n03=0.f, n10=0.f,n11=0.f,n12=0.f,n13=0.f;

#define CHAN(c, xa_c, sa_c, xb_c, sb_c)                                      \
    {                                                                        \
        const uint4 wv = wp[(c) * Tt + t];                                   \
        const float m0 = bflo(wv.x), m1 = bfhi(wv.x);                        \
        const float m2 = bflo(wv.y), m3 = bfhi(wv.y);                        \
        const float q0 = bflo(wv.z), q1 = bfhi(wv.z);                        \
        const float q2 = bflo(wv.w), q3 = bfhi(wv.w);                        \
        a00 = fmaf(xa_c, m0, a00); a01 = fmaf(xa_c, m1, a01);                \
        a02 = fmaf(xa_c, m2, a02); a03 = fmaf(xa_c, m3, a03);                \
        a10 = fmaf(xb_c, m0, a10); a11 = fmaf(xb_c, m1, a11);                \
        a12 = fmaf(xb_c, m2, a12); a13 = fmaf(xb_c, m3, a13);                \
        const float ya = (xa_c) * (sa_c);                                    \
        const float yb = (xb_c) * (sb_c);                                    \
        n00 = fmaf(ya, q0, n00); n01 = fmaf(ya, q1, n01);                    \
        n02 = fmaf(ya, q2, n02); n03 = fmaf(ya, q3, n03);                    \
        n10 = fmaf(yb, q0, n10); n11 = fmaf(yb, q1, n11);                    \
        n12 = fmaf(yb, q2, n12); n13 = fmaf(yb, q3, n13);                    \
    }

    #pragma unroll
    for (int kd = 0; kd < 3; ++kd) {
        #pragma unroll
        for (int kh = 0; kh < 3; ++kh) {
            const int roff = (kd * Dn + kh) * Dn;
            #pragma unroll
            for (int kw = 0; kw < 3; ++kw) {
                const int t = (kd * 3 + kh) * 3 + kw;
                const float4 xa = x4[v0 + roff + kw];
                const float4 sa = s4[v0 + roff + kw];
                const float4 xb = x4[v1 + roff + kw];
                const float4 sb = s4[v1 + roff + kw];
                CHAN(0, xa.x, sa.x, xb.x, sb.x);
                CHAN(1, xa.y, sa.y, xb.y, sb.y);
                CHAN(2, xa.z, sa.z, xb.z, sb.z);
                CHAN(3, xa.w, sa.w, xb.w, sb.w);
            }
        }
    }
#undef CHAN

    // ---- Epilogue: coalesced 64 B segments per b-group ----
    const float4 bi = *(const float4*)bias;
    const size_t ob0 = (size_t)b0 * Pn + p;
    const size_t ob1 = (size_t)b1 * Pn + p;
    const float4 so0 = ((const float4*)sgn_out)[ob0];
    const float4 so1 = ((const float4*)sgn_out)[ob1];
    float4 o0, o1;
    o0.x = fmaf(so0.x, n00, a00) + bi.x;
    o0.y = fmaf(so0.y, n01, a01) + bi.y;
    o0.z = fmaf(so0.z, n02, a02) + bi.z;
    o0.w = fmaf(so0.w, n03, a03) + bi.w;
    o1.x = fmaf(so1.x, n10, a10) + bi.x;
    o1.y = fmaf(so1.y, n11, a11) + bi.y;
    o1.z = fmaf(so1.z, n12, a12) + bi.z;
    o1.w = fmaf(so1.w, n13, a13) + bi.w;
    ((float4*)out)[ob0] = o0;
    ((float4*)out)[ob1] = o1;
}

extern "C" void kernel_launch(void* const* d_in, const int* in_sizes, int n_in,
                              void* d_out, int out_size, void* d_ws, size_t ws_size,
                              hipStream_t stream) {
    const float* x    = (const float*)d_in[0];
    const float* loc  = (const float*)d_in[1];
    const float* rho  = (const float*)d_in[2];
    const float* bias = (const float*)d_in[3];
    const float* eps  = (const float*)d_in[4];
    const float* si   = (const float*)d_in[5];
    const float* so   = (const float*)d_in[6];
    float* out = (float*)d_out;

    lc3d_flipout_kernel<<<dim3(NT), dim3(THREADS), 0, stream>>>(
        x, loc, rho, bias, eps, si, so, out);
}